// Round 3
// baseline (311.552 us; speedup 1.0000x reference)
//
#include <hip/hip_runtime.h>
#include <hip/hip_bf16.h>

typedef _Float16 h8 __attribute__((ext_vector_type(8)));
typedef float f4 __attribute__((ext_vector_type(4)));

#define N_TOK 65536
#define DIM 256
#define KCODES 1024
#define HWSZ 4096
#define TAU 0.125f
#define FCAP 8192

// async global->LDS, 16B per lane. LDS dest = wave-uniform base + lane*16.
__device__ __forceinline__ void gll16(const void* g, void* l) {
    __builtin_amdgcn_global_load_lds((const __attribute__((address_space(1))) void*)g,
                                     (__attribute__((address_space(3))) void*)l, 16, 0, 0);
}

// Fragment layout (A and B operands, 16x16x32 f16 MFMA):
//   element (n, d) -> granule G = ((n>>4)*8 + (d>>5))*64 + ((d>>3)&3)*16 + (n&15),
//   half j = d&7 inside the 16B granule. Conflict-free ds_read_b128, linear gll16.

// ---------------- K0a: embedding -> fragment-layout fp16 hi -----------------
__global__ void k_prep_frag(const float* __restrict__ emb, _Float16* __restrict__ BhF) {
    int gi = blockIdx.x * 256 + threadIdx.x;      // granule index, 0..32767
    int kb = gi >> 9;
    int s = (gi >> 6) & 7;
    int dq = (gi >> 4) & 3;
    int r = gi & 15;
    int code = kb * 16 + r;
    int d0 = s * 32 + dq * 8;
    const float* src = emb + (size_t)code * DIM + d0;
    float4 x0 = *(const float4*)(src);
    float4 x1 = *(const float4*)(src + 4);
    float xs[8] = {x0.x, x0.y, x0.z, x0.w, x1.x, x1.y, x1.z, x1.w};
    h8 hi;
#pragma unroll
    for (int j = 0; j < 8; ++j) hi[j] = (_Float16)xs[j];
    *(h8*)(BhF + (size_t)gi * 8) = hi;
}

// ---------------- K0b: e_sq (+ zero flag counter) ----------------------------
__global__ void k_esq(const float* __restrict__ emb, float* __restrict__ e_sq,
                      int* __restrict__ flagCnt) {
    if (blockIdx.x == 0 && threadIdx.x == 0) *flagCnt = 0;
    int t = threadIdx.x;
    int code = blockIdx.x * 4 + (t >> 6);
    int l = t & 63;
    float4 v = *(const float4*)(emb + (size_t)code * DIM + l * 4);
    float s = v.x * v.x + v.y * v.y + v.z * v.z + v.w * v.w;
#pragma unroll
    for (int off = 32; off >= 1; off >>= 1) s += __shfl_xor(s, off);
    if (l == 0) e_sq[code] = s;
}

// ------- K1: transpose z[B,C,H,W] -> enc[N,C] + fragment fp16 hi -------------
__global__ void k_transpose(const float* __restrict__ z, float* __restrict__ enc,
                            _Float16* __restrict__ AhF) {
    __shared__ float T[64][65];
    int blk = blockIdx.x;
    int b = blk >> 8;
    int rem = blk & 255;
    int c0 = (rem >> 6) * 64;
    int hw0 = (rem & 63) * 64;
    int t = threadIdx.x;
    const float* zp = z + (size_t)b * DIM * HWSZ;
    {
        int hw4 = (t & 15) * 4, cl = t >> 4;
#pragma unroll
        for (int i = 0; i < 4; ++i) {
            int c = cl + i * 16;
            float4 v = *(const float4*)(zp + (size_t)(c0 + c) * HWSZ + hw0 + hw4);
            T[c][hw4 + 0] = v.x; T[c][hw4 + 1] = v.y;
            T[c][hw4 + 2] = v.z; T[c][hw4 + 3] = v.w;
        }
    }
    __syncthreads();
    // enc fp32 (output 0)
    {
        int c4 = (t & 15) * 4, hwl = t >> 4;
#pragma unroll
        for (int i = 0; i < 4; ++i) {
            int hw = hwl + i * 16;
            float4 v;
            v.x = T[c4 + 0][hw]; v.y = T[c4 + 1][hw];
            v.z = T[c4 + 2][hw]; v.w = T[c4 + 3][hw];
            *(float4*)(enc + (size_t)(b * HWSZ + hw0 + hw) * DIM + c0 + c4) = v;
        }
    }
    // fragment-layout fp16 hi
    {
        int base_nb = b * 256 + (hw0 >> 4);
#pragma unroll
        for (int i = 0; i < 2; ++i) {
            int gidx = i * 256 + t;
            int nbi = gidx >> 7;
            int si = (gidx >> 6) & 1;
            int dq = (gidx >> 4) & 3;
            int r = gidx & 15;
            int hwl = nbi * 16 + r;
            int cl = si * 32 + dq * 8;
            h8 hi;
#pragma unroll
            for (int j = 0; j < 8; ++j) hi[j] = (_Float16)T[cl + j][hwl];
            size_t G = (((size_t)(base_nb + nbi) * 8) + (c0 >> 5) + si) * 64 + dq * 16 + r;
            *(h8*)(AhF + G * 8) = hi;
        }
    }
}

// -------- K2: GEMM (fp16 hi, 1 pass, double-buffered) + argmin top-2 ---------
__global__ __launch_bounds__(512)
void k_gemm_argmin(const _Float16* __restrict__ AhF, const _Float16* __restrict__ BhF,
                   const float* __restrict__ e_sq,
                   float* __restrict__ pV1, int* __restrict__ pI1,
                   float* __restrict__ pV2) {
    __shared__ _Float16 S[2][12288];  // per buf: A halves [0,4096), B [4096,12288)

    int gid = blockIdx.x;
    int colTile = gid >> 9, rowTile = gid & 511;
    int r0 = rowTile * 128, c0 = colTile * 256;
    int t = threadIdx.x;
    int w = t >> 6, l = t & 63;
    int wm = w >> 2, wn = w & 3;
    int l16 = l & 15, lhi = l >> 4;

    const char* gA = (const char*)AhF + (((size_t)(rowTile * 8 + w)) << 13) + (l << 4);
    const char* gB0 = (const char*)BhF + (((size_t)(colTile * 16 + w)) << 13) + (l << 4);
    const char* gB1 = gB0 + (8ll << 13);
    int aoff = w << 10;                  // bytes, wave-uniform LDS dest
    int boff0 = 8192 + (w << 10);
    int boff1 = 8192 + ((8 + w) << 10);

    f4 acc[4][4];
#pragma unroll
    for (int i = 0; i < 4; ++i)
#pragma unroll
        for (int j = 0; j < 4; ++j) acc[i][j] = (f4)0.0f;

    // prologue: stage step 0 into buf 0
    gll16(gA, (char*)S[0] + aoff);
    gll16(gB0, (char*)S[0] + boff0);
    gll16(gB1, (char*)S[0] + boff1);
    __syncthreads();

    for (int s = 0; s < 8; ++s) {
        int cur = s & 1;
        if (s < 7) {  // issue next-step stage early; the end-of-step barrier drains it
            size_t so = (size_t)(s + 1) << 10;
            gll16(gA + so, (char*)S[cur ^ 1] + aoff);
            gll16(gB0 + so, (char*)S[cur ^ 1] + boff0);
            gll16(gB1 + so, (char*)S[cur ^ 1] + boff1);
        }
        h8 ah[4], bh[4];
#pragma unroll
        for (int mf = 0; mf < 4; ++mf)
            ah[mf] = *(const h8*)((const char*)S[cur] + (((wm * 4 + mf) << 10) + (l << 4)));
#pragma unroll
        for (int nf = 0; nf < 4; ++nf)
            bh[nf] = *(const h8*)((const char*)S[cur] + 8192 + (((wn * 4 + nf) << 10) + (l << 4)));
#pragma unroll
        for (int mf = 0; mf < 4; ++mf)
#pragma unroll
            for (int nf = 0; nf < 4; ++nf)
                acc[mf][nf] = __builtin_amdgcn_mfma_f32_16x16x32_f16(ah[mf], bh[nf], acc[mf][nf], 0, 0, 0);
        __syncthreads();
    }

    // ---- scores + per-row (best, idx, second-best) over this block's 256 codes
    float* smV1 = (float*)S[0];          // [4][128]
    int* smI1 = (int*)S[0] + 512;
    float* smV2 = (float*)S[0] + 1024;

    float esq[4];
#pragma unroll
    for (int nf = 0; nf < 4; ++nf) esq[nf] = e_sq[c0 + wn * 64 + nf * 16 + l16];

#pragma unroll
    for (int mf = 0; mf < 4; ++mf) {
#pragma unroll
        for (int rg = 0; rg < 4; ++rg) {
            float v1 = 3.4e38f, v2 = 3.4e38f;
            int i1 = 0;
#pragma unroll
            for (int nf = 0; nf < 4; ++nf) {
                float v = esq[nf] - 2.0f * acc[mf][nf][rg];
                int ci = c0 + wn * 64 + nf * 16 + l16;
                if (v < v1 || (v == v1 && ci < i1)) { v2 = v1; v1 = v; i1 = ci; }
                else v2 = fminf(v2, v);
            }
#pragma unroll
            for (int off = 1; off < 16; off <<= 1) {
                float ov1 = __shfl_xor(v1, off);
                int oi1 = __shfl_xor(i1, off);
                float ov2 = __shfl_xor(v2, off);
                if (ov1 < v1 || (ov1 == v1 && oi1 < i1)) { v2 = fminf(v1, ov2); v1 = ov1; i1 = oi1; }
                else v2 = fminf(v2, ov1);
            }
            if (l16 == 0) {
                int rloc = wm * 64 + mf * 16 + lhi * 4 + rg;
                smV1[wn * 128 + rloc] = v1;
                smI1[wn * 128 + rloc] = i1;
                smV2[wn * 128 + rloc] = v2;
            }
        }
    }
    __syncthreads();
    if (t < 128) {
        float v1 = smV1[t], v2 = smV2[t];
        int i1 = smI1[t];
#pragma unroll
        for (int wn2 = 1; wn2 < 4; ++wn2) {
            float a1 = smV1[wn2 * 128 + t];
            int ai = smI1[wn2 * 128 + t];
            float a2 = smV2[wn2 * 128 + t];
            if (a1 < v1 || (a1 == v1 && ai < i1)) { v2 = fminf(v1, a2); v1 = a1; i1 = ai; }
            else v2 = fminf(v2, a1);
        }
        pV1[colTile * N_TOK + r0 + t] = v1;
        pI1[colTile * N_TOK + r0 + t] = i1;
        pV2[colTile * N_TOK + r0 + t] = v2;
    }
}

// -------- K3a: combine partials -> final index + flag ambiguous rows ---------
__global__ void k_final_idx(const float* __restrict__ pV1, const int* __restrict__ pI1,
                            const float* __restrict__ pV2,
                            float* __restrict__ out2, int* __restrict__ idxI,
                            int* __restrict__ flagCnt, int* __restrict__ flagList) {
    int n = blockIdx.x * 256 + threadIdx.x;
    float v1 = pV1[n], v2 = pV2[n];
    int i1 = pI1[n];
#pragma unroll
    for (int ct = 1; ct < 4; ++ct) {
        float a1 = pV1[ct * N_TOK + n];
        int ai = pI1[ct * N_TOK + n];
        float a2 = pV2[ct * N_TOK + n];
        if (a1 < v1 || (a1 == v1 && ai < i1)) { v2 = fminf(v1, a2); v1 = a1; i1 = ai; }
        else v2 = fminf(v2, a1);
    }
    out2[n] = (float)i1;
    idxI[n] = i1;
    if (v2 - v1 < TAU) {
        int p = atomicAdd(flagCnt, 1);
        if (p < FCAP) flagList[p] = n;
    }
}

// -------- K3b: exact fp32 rescore of flagged rows ----------------------------
__global__ __launch_bounds__(512)
void k_rescore(const float* __restrict__ enc, const float* __restrict__ emb,
               const int* __restrict__ flagCnt, const int* __restrict__ flagList,
               float* __restrict__ out2, int* __restrict__ idxI) {
    __shared__ float sv[8];
    __shared__ int si[8];
    int cnt = *flagCnt;
    if (cnt > FCAP) cnt = FCAP;
    int t = threadIdx.x, w = t >> 6, l = t & 63;
    for (int j = blockIdx.x; j < cnt; j += gridDim.x) {
        int row = flagList[j];
        f4 x = *(const f4*)(enc + (size_t)row * DIM + l * 4);
        float bv = 3.4e38f;
        int bi = 0;
        for (int c = w; c < KCODES; c += 8) {
            f4 e = *(const f4*)(emb + (size_t)c * DIM + l * 4);
            // per-lane partial of (||e||^2 - 2 x.e)
            float p = e[0] * (e[0] - 2.0f * x[0]) + e[1] * (e[1] - 2.0f * x[1]) +
                      e[2] * (e[2] - 2.0f * x[2]) + e[3] * (e[3] - 2.0f * x[3]);
#pragma unroll
            for (int off = 32; off >= 1; off >>= 1) p += __shfl_xor(p, off);
            if (p < bv) { bv = p; bi = c; }  // c increasing per wave -> keeps lowest
        }
        if (l == 0) { sv[w] = bv; si[w] = bi; }
        __syncthreads();
        if (t == 0) {
            float fv = sv[0];
            int fi = si[0];
#pragma unroll
            for (int k = 1; k < 8; ++k) {
                if (sv[k] < fv || (sv[k] == fv && si[k] < fi)) { fv = sv[k]; fi = si[k]; }
            }
            out2[row] = (float)fi;
            idxI[row] = fi;
        }
        __syncthreads();
    }
}

// ---------------- K4a: quantized_flat[N,D] = embedding[idx] ------------------
__global__ void k_out1(const float* __restrict__ emb, const int* __restrict__ idxI,
                       float* __restrict__ out1) {
    int t = threadIdx.x;
    int r = blockIdx.x * 64 + (t >> 2), q = t & 3;
    int idx = idxI[r];
    const float* src = emb + (size_t)idx * DIM + q * 64;
    float* dst = out1 + (size_t)r * DIM + q * 64;
#pragma unroll
    for (int i = 0; i < 16; ++i)
        *(float4*)(dst + i * 4) = *(const float4*)(src + i * 4);
}

// ---------------- K4b: quantized[B,C,H,W] via LDS transpose ------------------
__global__ void k_out3(const float* __restrict__ emb, const int* __restrict__ idxI,
                       float* __restrict__ out3) {
    __shared__ float E[32][257];
    int blk = blockIdx.x;
    int b = blk >> 7, hwt = blk & 127;
    int hw0 = hwt * 32;
    int n0 = b * HWSZ + hw0;
    int t = threadIdx.x;
    {
        int r = t >> 3, oct = t & 7;
        int idx = idxI[n0 + r];
        const float* src = emb + (size_t)idx * DIM + oct * 32;
#pragma unroll
        for (int i = 0; i < 8; ++i) {
            float4 v = *(const float4*)(src + i * 4);
            E[r][oct * 32 + i * 4 + 0] = v.x;
            E[r][oct * 32 + i * 4 + 1] = v.y;
            E[r][oct * 32 + i * 4 + 2] = v.z;
            E[r][oct * 32 + i * 4 + 3] = v.w;
        }
    }
    __syncthreads();
    {
        int w = t >> 6, l = t & 63;
        int ch = l >> 5, hw = l & 31;
        float* dst = out3 + (size_t)b * DIM * HWSZ + hw0 + hw;
#pragma unroll
        for (int it = 0; it < 32; ++it) {
            int c = w * 64 + it * 2 + ch;
            dst[(size_t)c * HWSZ] = E[hw][c];
        }
    }
}

extern "C" void kernel_launch(void* const* d_in, const int* in_sizes, int n_in,
                              void* d_out, int out_size, void* d_ws, size_t ws_size,
                              hipStream_t stream) {
    const float* z = (const float*)d_in[0];
    const float* emb = (const float*)d_in[1];
    float* out = (float*)d_out;
    float* out0 = out;                    // encoded_flat  [65536,256]
    float* out1 = out + 16777216;         // quantized_flat[65536,256]
    float* out2 = out + 33554432;         // indices       [65536] (as float)
    float* out3 = out + 33619968;         // quantized     [16,256,64,64]

    // Bulky scratch lives in the out1 region (64 MB), written last by k_out1:
    //   AhF (32 MB) + partials (3 MB).
    _Float16* AhF = (_Float16*)out1;
    float* pV1 = out1 + 8388608;          // +32 MB
    int* pI1 = (int*)(out1 + 8650752);
    float* pV2 = out1 + 8912896;

    char* ws = (char*)d_ws;
    _Float16* BhF = (_Float16*)(ws);                 // 512 KB
    float* e_sq = (float*)(ws + 524288);             // 4 KB
    int* flagCnt = (int*)(ws + 528384);              // 4 B
    int* flagList = (int*)(ws + 532480);             // 32 KB
    int* idxI = (int*)(ws + 565248);                 // 256 KB

    k_prep_frag<<<128, 256, 0, stream>>>(emb, BhF);
    k_esq<<<256, 256, 0, stream>>>(emb, e_sq, flagCnt);
    k_transpose<<<4096, 256, 0, stream>>>(z, out0, AhF);
    k_gemm_argmin<<<2048, 512, 0, stream>>>(AhF, BhF, e_sq, pV1, pI1, pV2);
    k_final_idx<<<256, 256, 0, stream>>>(pV1, pI1, pV2, out2, idxI, flagCnt, flagList);
    k_rescore<<<512, 512, 0, stream>>>(out0, emb, flagCnt, flagList, out2, idxI);
    k_out1<<<1024, 256, 0, stream>>>(emb, idxI, out1);
    k_out3<<<2048, 256, 0, stream>>>(emb, idxI, out3);
}

// Round 4
// 275.283 us; speedup vs baseline: 1.1318x; 1.1318x over previous
//
#include <hip/hip_runtime.h>
#include <hip/hip_bf16.h>

typedef _Float16 h8 __attribute__((ext_vector_type(8)));
typedef float f4 __attribute__((ext_vector_type(4)));

#define N_TOK 65536
#define DIM 256
#define KCODES 1024
#define HWSZ 4096

// Fragment layout (A and B operands, 16x16x32 f16 MFMA):
//   element (n, d) -> granule G = ((n>>4)*8 + (d>>5))*64 + ((d>>3)&3)*16 + (n&15),
//   half j = d&7 inside the 16B granule (granule = 16 bytes).
// A wave's fragment (16 rows x 32 d) is 64 consecutive granules = 1KB, so a
// global_load_dwordx4 at base + lane*16 is perfectly coalesced.

// ---------------- K0a: embedding -> fragment-layout fp16 hi/lo ---------------
__global__ void k_prep_frag(const float* __restrict__ emb, _Float16* __restrict__ BhF,
                            _Float16* __restrict__ BlF) {
    int gi = blockIdx.x * 256 + threadIdx.x;      // granule index, 0..32767
    int kb = gi >> 9;
    int s = (gi >> 6) & 7;
    int dq = (gi >> 4) & 3;
    int r = gi & 15;
    int code = kb * 16 + r;
    int d0 = s * 32 + dq * 8;
    const float* src = emb + (size_t)code * DIM + d0;
    float4 x0 = *(const float4*)(src);
    float4 x1 = *(const float4*)(src + 4);
    float xs[8] = {x0.x, x0.y, x0.z, x0.w, x1.x, x1.y, x1.z, x1.w};
    h8 hi, lo;
#pragma unroll
    for (int j = 0; j < 8; ++j) {
        _Float16 h = (_Float16)xs[j];
        hi[j] = h;
        lo[j] = (_Float16)(xs[j] - (float)h);
    }
    *(h8*)(BhF + (size_t)gi * 8) = hi;
    *(h8*)(BlF + (size_t)gi * 8) = lo;
}

// ---------------- K0b: e_sq ---------------------------------------------------
__global__ void k_esq(const float* __restrict__ emb, float* __restrict__ e_sq) {
    int t = threadIdx.x;
    int code = blockIdx.x * 4 + (t >> 6);
    int l = t & 63;
    float4 v = *(const float4*)(emb + (size_t)code * DIM + l * 4);
    float s = v.x * v.x + v.y * v.y + v.z * v.z + v.w * v.w;
#pragma unroll
    for (int off = 32; off >= 1; off >>= 1) s += __shfl_xor(s, off);
    if (l == 0) e_sq[code] = s;
}

// ------- K1: transpose z[B,C,H,W] -> enc[N,C] + fragment fp16 hi/lo ----------
__global__ void k_transpose(const float* __restrict__ z, float* __restrict__ enc,
                            _Float16* __restrict__ AhF, _Float16* __restrict__ AlF) {
    __shared__ float T[64][65];
    int blk = blockIdx.x;
    int b = blk >> 8;
    int rem = blk & 255;
    int c0 = (rem >> 6) * 64;
    int hw0 = (rem & 63) * 64;
    int t = threadIdx.x;
    const float* zp = z + (size_t)b * DIM * HWSZ;
    {
        int hw4 = (t & 15) * 4, cl = t >> 4;
#pragma unroll
        for (int i = 0; i < 4; ++i) {
            int c = cl + i * 16;
            float4 v = *(const float4*)(zp + (size_t)(c0 + c) * HWSZ + hw0 + hw4);
            T[c][hw4 + 0] = v.x; T[c][hw4 + 1] = v.y;
            T[c][hw4 + 2] = v.z; T[c][hw4 + 3] = v.w;
        }
    }
    __syncthreads();
    // enc fp32 (output 0)
    {
        int c4 = (t & 15) * 4, hwl = t >> 4;
#pragma unroll
        for (int i = 0; i < 4; ++i) {
            int hw = hwl + i * 16;
            float4 v;
            v.x = T[c4 + 0][hw]; v.y = T[c4 + 1][hw];
            v.z = T[c4 + 2][hw]; v.w = T[c4 + 3][hw];
            *(float4*)(enc + (size_t)(b * HWSZ + hw0 + hw) * DIM + c0 + c4) = v;
        }
    }
    // fragment-layout fp16 hi/lo
    {
        int base_nb = b * 256 + (hw0 >> 4);
#pragma unroll
        for (int i = 0; i < 2; ++i) {
            int gidx = i * 256 + t;
            int nbi = gidx >> 7;
            int si = (gidx >> 6) & 1;
            int dq = (gidx >> 4) & 3;
            int r = gidx & 15;
            int hwl = nbi * 16 + r;
            int cl = si * 32 + dq * 8;
            h8 hi, lo;
#pragma unroll
            for (int j = 0; j < 8; ++j) {
                float x = T[cl + j][hwl];
                _Float16 h = (_Float16)x;
                hi[j] = h;
                lo[j] = (_Float16)(x - (float)h);
            }
            size_t G = (((size_t)(base_nb + nbi) * 8) + (c0 >> 5) + si) * 64 + dq * 16 + r;
            *(h8*)(AhF + G * 8) = hi;
            *(h8*)(AlF + G * 8) = lo;
        }
    }
}

// -------- K2: all-register GEMM (fp16 split, 3 passes) + fused argmin --------
__global__ __launch_bounds__(512)
void k_gemm_argmin(const _Float16* __restrict__ AhF, const _Float16* __restrict__ AlF,
                   const _Float16* __restrict__ BhF, const _Float16* __restrict__ BlF,
                   const float* __restrict__ e_sq,
                   float* __restrict__ pV1, int* __restrict__ pI1) {
    __shared__ float smV[512];
    __shared__ int smI[512];

    int gid = blockIdx.x;
    int colTile = gid >> 9, rowTile = gid & 511;
    int r0 = rowTile * 128, c0 = colTile * 256;
    int t = threadIdx.x;
    int w = t >> 6, l = t & 63;
    int wm = w >> 2, wn = w & 3;
    int l16 = l & 15, lhi = l >> 4;

    // fragment byte address: ((nb*8 + s) << 10) + l*16 = (nb<<13) + (s<<10) + l*16
    const char* pAh = (const char*)AhF + (((size_t)(rowTile * 8 + wm * 4)) << 13) + (l << 4);
    const char* pAl = (const char*)AlF + (((size_t)(rowTile * 8 + wm * 4)) << 13) + (l << 4);
    const char* pBh = (const char*)BhF + (((size_t)(colTile * 16 + wn * 4)) << 13) + (l << 4);
    const char* pBl = (const char*)BlF + (((size_t)(colTile * 16 + wn * 4)) << 13) + (l << 4);

    f4 acc[4][4];
#pragma unroll
    for (int i = 0; i < 4; ++i)
#pragma unroll
        for (int j = 0; j < 4; ++j) acc[i][j] = (f4)0.0f;

#pragma unroll 2
    for (int s = 0; s < 8; ++s) {
        int off = s << 10;
        h8 ah[4], bh[4];
#pragma unroll
        for (int mf = 0; mf < 4; ++mf) ah[mf] = *(const h8*)(pAh + (mf << 13) + off);
#pragma unroll
        for (int nf = 0; nf < 4; ++nf) bh[nf] = *(const h8*)(pBh + (nf << 13) + off);
#pragma unroll
        for (int mf = 0; mf < 4; ++mf)
#pragma unroll
            for (int nf = 0; nf < 4; ++nf)
                acc[mf][nf] = __builtin_amdgcn_mfma_f32_16x16x32_f16(ah[mf], bh[nf], acc[mf][nf], 0, 0, 0);
        h8 al[4];
#pragma unroll
        for (int mf = 0; mf < 4; ++mf) al[mf] = *(const h8*)(pAl + (mf << 13) + off);
#pragma unroll
        for (int mf = 0; mf < 4; ++mf)
#pragma unroll
            for (int nf = 0; nf < 4; ++nf)
                acc[mf][nf] = __builtin_amdgcn_mfma_f32_16x16x32_f16(al[mf], bh[nf], acc[mf][nf], 0, 0, 0);
        h8 bl[4];
#pragma unroll
        for (int nf = 0; nf < 4; ++nf) bl[nf] = *(const h8*)(pBl + (nf << 13) + off);
#pragma unroll
        for (int mf = 0; mf < 4; ++mf)
#pragma unroll
            for (int nf = 0; nf < 4; ++nf)
                acc[mf][nf] = __builtin_amdgcn_mfma_f32_16x16x32_f16(ah[mf], bl[nf], acc[mf][nf], 0, 0, 0);
    }

    // ---- scores + per-row argmin over this block's 256 codes ----
    float esq[4];
#pragma unroll
    for (int nf = 0; nf < 4; ++nf) esq[nf] = e_sq[c0 + wn * 64 + nf * 16 + l16];

#pragma unroll
    for (int mf = 0; mf < 4; ++mf) {
#pragma unroll
        for (int rg = 0; rg < 4; ++rg) {
            float bestV = 3.4e38f;
            int bestI = 0;
#pragma unroll
            for (int nf = 0; nf < 4; ++nf) {
                float v = esq[nf] - 2.0f * acc[mf][nf][rg];
                int ci = c0 + wn * 64 + nf * 16 + l16;
                if (v < bestV || (v == bestV && ci < bestI)) { bestV = v; bestI = ci; }
            }
#pragma unroll
            for (int off = 1; off < 16; off <<= 1) {
                float vv = __shfl_xor(bestV, off);
                int ii = __shfl_xor(bestI, off);
                if (vv < bestV || (vv == bestV && ii < bestI)) { bestV = vv; bestI = ii; }
            }
            if (l16 == 0) {
                int rloc = wm * 64 + mf * 16 + lhi * 4 + rg;
                smV[wn * 128 + rloc] = bestV;
                smI[wn * 128 + rloc] = bestI;
            }
        }
    }
    __syncthreads();
    if (t < 128) {
        float bestV = smV[t];
        int bestI = smI[t];
#pragma unroll
        for (int wn2 = 1; wn2 < 4; ++wn2) {
            float v = smV[wn2 * 128 + t];
            int i2 = smI[wn2 * 128 + t];
            if (v < bestV || (v == bestV && i2 < bestI)) { bestV = v; bestI = i2; }
        }
        pV1[colTile * N_TOK + r0 + t] = bestV;
        pI1[colTile * N_TOK + r0 + t] = bestI;
    }
}

// ---------------- K3: combine partials -> final index ------------------------
__global__ void k_final_idx(const float* __restrict__ pV1, const int* __restrict__ pI1,
                            float* __restrict__ out2, int* __restrict__ idxI) {
    int n = blockIdx.x * 256 + threadIdx.x;
    float v1 = pV1[n];
    int i1 = pI1[n];
#pragma unroll
    for (int ct = 1; ct < 4; ++ct) {
        float a1 = pV1[ct * N_TOK + n];
        int ai = pI1[ct * N_TOK + n];
        if (a1 < v1 || (a1 == v1 && ai < i1)) { v1 = a1; i1 = ai; }
    }
    out2[n] = (float)i1;
    idxI[n] = i1;
}

// ---------------- K4a: quantized_flat[N,D] = embedding[idx] ------------------
__global__ void k_out1(const float* __restrict__ emb, const int* __restrict__ idxI,
                       float* __restrict__ out1) {
    int t = threadIdx.x;
    int r = blockIdx.x * 64 + (t >> 2), q = t & 3;
    int idx = idxI[r];
    const float* src = emb + (size_t)idx * DIM + q * 64;
    float* dst = out1 + (size_t)r * DIM + q * 64;
#pragma unroll
    for (int i = 0; i < 16; ++i)
        *(float4*)(dst + i * 4) = *(const float4*)(src + i * 4);
}

// ---------------- K4b: quantized[B,C,H,W] via LDS transpose ------------------
__global__ void k_out3(const float* __restrict__ emb, const int* __restrict__ idxI,
                       float* __restrict__ out3) {
    __shared__ float E[32][257];
    int blk = blockIdx.x;
    int b = blk >> 7, hwt = blk & 127;
    int hw0 = hwt * 32;
    int n0 = b * HWSZ + hw0;
    int t = threadIdx.x;
    {
        int r = t >> 3, oct = t & 7;
        int idx = idxI[n0 + r];
        const float* src = emb + (size_t)idx * DIM + oct * 32;
#pragma unroll
        for (int i = 0; i < 8; ++i) {
            float4 v = *(const float4*)(src + i * 4);
            E[r][oct * 32 + i * 4 + 0] = v.x;
            E[r][oct * 32 + i * 4 + 1] = v.y;
            E[r][oct * 32 + i * 4 + 2] = v.z;
            E[r][oct * 32 + i * 4 + 3] = v.w;
        }
    }
    __syncthreads();
    {
        int w = t >> 6, l = t & 63;
        int ch = l >> 5, hw = l & 31;
        float* dst = out3 + (size_t)b * DIM * HWSZ + hw0 + hw;
#pragma unroll
        for (int it = 0; it < 32; ++it) {
            int c = w * 64 + it * 2 + ch;
            dst[(size_t)c * HWSZ] = E[hw][c];
        }
    }
}

extern "C" void kernel_launch(void* const* d_in, const int* in_sizes, int n_in,
                              void* d_out, int out_size, void* d_ws, size_t ws_size,
                              hipStream_t stream) {
    const float* z = (const float*)d_in[0];
    const float* emb = (const float*)d_in[1];
    float* out = (float*)d_out;
    float* out0 = out;                    // encoded_flat  [65536,256]
    float* out1 = out + 16777216;         // quantized_flat[65536,256]
    float* out2 = out + 33554432;         // indices       [65536] (as float)
    float* out3 = out + 33619968;         // quantized     [16,256,64,64]

    // A-operand fp16 hi/lo scratch fills the out1 region exactly (64 MB);
    // out1 is written last by k_out1.
    _Float16* AhF = (_Float16*)out1;
    _Float16* AlF = (_Float16*)(out1 + 8388608);

    char* ws = (char*)d_ws;
    _Float16* BhF = (_Float16*)(ws);                 // 512 KB
    _Float16* BlF = (_Float16*)(ws + 524288);        // 512 KB
    float* e_sq = (float*)(ws + 1048576);            // 4 KB
    float* pV1 = (float*)(ws + 1052672);             // 1 MB
    int* pI1 = (int*)(ws + 2101248);                 // 1 MB
    int* idxI = (int*)(ws + 3149824);                // 256 KB

    k_prep_frag<<<128, 256, 0, stream>>>(emb, BhF, BlF);
    k_esq<<<256, 256, 0, stream>>>(emb, e_sq);
    k_transpose<<<4096, 256, 0, stream>>>(z, out0, AhF, AlF);
    k_gemm_argmin<<<2048, 512, 0, stream>>>(AhF, AlF, BhF, BlF, e_sq, pV1, pI1);
    k_final_idx<<<256, 256, 0, stream>>>(pV1, pI1, out2, idxI);
    k_out1<<<1024, 256, 0, stream>>>(emb, idxI, out1);
    k_out3<<<2048, 256, 0, stream>>>(emb, idxI, out3);
}

// Round 5
// 254.510 us; speedup vs baseline: 1.2241x; 1.0816x over previous
//
#include <hip/hip_runtime.h>
#include <hip/hip_bf16.h>

typedef _Float16 h8 __attribute__((ext_vector_type(8)));
typedef float f4 __attribute__((ext_vector_type(4)));

#define N_TOK 65536
#define DIM 256
#define KCODES 1024
#define HWSZ 4096

// async global->LDS, 16B per lane. LDS dest = wave-uniform base + lane*16.
__device__ __forceinline__ void gll16(const void* g, void* l) {
    __builtin_amdgcn_global_load_lds((const __attribute__((address_space(1))) void*)g,
                                     (__attribute__((address_space(3))) void*)l, 16, 0, 0);
}

// Fragment layout (A and B operands, 16x16x32 f16 MFMA):
//   element (n, d) -> granule G = ((n>>4)*8 + (d>>5))*64 + ((d>>3)&3)*16 + (n&15),
//   half j = d&7 inside the 16B granule. Conflict-free ds_read_b128, linear gll16.

// ---------------- K0a: embedding -> fragment-layout fp16 hi/lo ---------------
__global__ void k_prep_frag(const float* __restrict__ emb, _Float16* __restrict__ BhF,
                            _Float16* __restrict__ BlF) {
    int gi = blockIdx.x * 256 + threadIdx.x;      // granule index, 0..32767
    int kb = gi >> 9;
    int s = (gi >> 6) & 7;
    int dq = (gi >> 4) & 3;
    int r = gi & 15;
    int code = kb * 16 + r;
    int d0 = s * 32 + dq * 8;
    const float* src = emb + (size_t)code * DIM + d0;
    float4 x0 = *(const float4*)(src);
    float4 x1 = *(const float4*)(src + 4);
    float xs[8] = {x0.x, x0.y, x0.z, x0.w, x1.x, x1.y, x1.z, x1.w};
    h8 hi, lo;
#pragma unroll
    for (int j = 0; j < 8; ++j) {
        _Float16 h = (_Float16)xs[j];
        hi[j] = h;
        lo[j] = (_Float16)(xs[j] - (float)h);
    }
    *(h8*)(BhF + (size_t)gi * 8) = hi;
    *(h8*)(BlF + (size_t)gi * 8) = lo;
}

// ---------------- K0b: e_sq ---------------------------------------------------
__global__ void k_esq(const float* __restrict__ emb, float* __restrict__ e_sq) {
    int t = threadIdx.x;
    int code = blockIdx.x * 4 + (t >> 6);
    int l = t & 63;
    float4 v = *(const float4*)(emb + (size_t)code * DIM + l * 4);
    float s = v.x * v.x + v.y * v.y + v.z * v.z + v.w * v.w;
#pragma unroll
    for (int off = 32; off >= 1; off >>= 1) s += __shfl_xor(s, off);
    if (l == 0) e_sq[code] = s;
}

// ------- K1: transpose z[B,C,H,W] -> enc[N,C] + fragment fp16 hi/lo ----------
__global__ void k_transpose(const float* __restrict__ z, float* __restrict__ enc,
                            _Float16* __restrict__ AhF, _Float16* __restrict__ AlF) {
    __shared__ float T[64][65];
    int blk = blockIdx.x;
    int b = blk >> 8;
    int rem = blk & 255;
    int c0 = (rem >> 6) * 64;
    int hw0 = (rem & 63) * 64;
    int t = threadIdx.x;
    const float* zp = z + (size_t)b * DIM * HWSZ;
    {
        int hw4 = (t & 15) * 4, cl = t >> 4;
#pragma unroll
        for (int i = 0; i < 4; ++i) {
            int c = cl + i * 16;
            float4 v = *(const float4*)(zp + (size_t)(c0 + c) * HWSZ + hw0 + hw4);
            T[c][hw4 + 0] = v.x; T[c][hw4 + 1] = v.y;
            T[c][hw4 + 2] = v.z; T[c][hw4 + 3] = v.w;
        }
    }
    __syncthreads();
    // enc fp32 (output 0)
    {
        int c4 = (t & 15) * 4, hwl = t >> 4;
#pragma unroll
        for (int i = 0; i < 4; ++i) {
            int hw = hwl + i * 16;
            float4 v;
            v.x = T[c4 + 0][hw]; v.y = T[c4 + 1][hw];
            v.z = T[c4 + 2][hw]; v.w = T[c4 + 3][hw];
            *(float4*)(enc + (size_t)(b * HWSZ + hw0 + hw) * DIM + c0 + c4) = v;
        }
    }
    // fragment-layout fp16 hi/lo
    {
        int base_nb = b * 256 + (hw0 >> 4);
#pragma unroll
        for (int i = 0; i < 2; ++i) {
            int gidx = i * 256 + t;
            int nbi = gidx >> 7;
            int si = (gidx >> 6) & 1;
            int dq = (gidx >> 4) & 3;
            int r = gidx & 15;
            int hwl = nbi * 16 + r;
            int cl = si * 32 + dq * 8;
            h8 hi, lo;
#pragma unroll
            for (int j = 0; j < 8; ++j) {
                float x = T[cl + j][hwl];
                _Float16 h = (_Float16)x;
                hi[j] = h;
                lo[j] = (_Float16)(x - (float)h);
            }
            size_t G = (((size_t)(base_nb + nbi) * 8) + (c0 >> 5) + si) * 64 + dq * 16 + r;
            *(h8*)(AhF + G * 8) = hi;
            *(h8*)(AlF + G * 8) = lo;
        }
    }
}

// ---- K2: GEMM (fp16 split, 3 passes), 4-buf rotation, counted vmcnt ---------
#define WAITV(n) asm volatile("s_waitcnt vmcnt(" #n ")" ::: "memory")
#define BARRIER __builtin_amdgcn_s_barrier()

__global__ __launch_bounds__(512)
void k_gemm_argmin(const _Float16* __restrict__ AhF, const _Float16* __restrict__ AlF,
                   const _Float16* __restrict__ BhF, const _Float16* __restrict__ BlF,
                   const float* __restrict__ e_sq,
                   float* __restrict__ pV1, int* __restrict__ pI1) {
    __shared__ _Float16 S[49152];   // 96 KB = 4 bufs x 24 KB ([A 8K][B 16K])

    int gid = blockIdx.x;
    int colTile = gid >> 9, rowTile = gid & 511;
    int r0 = rowTile * 128, c0 = colTile * 256;
    int t = threadIdx.x;
    int w = t >> 6, l = t & 63;
    int wm = w >> 2, wn = w & 3;
    int l16 = l & 15, lhi = l >> 4;

    const char* gAh = (const char*)AhF + (((size_t)(rowTile * 8 + w)) << 13) + (l << 4);
    const char* gAl = (const char*)AlF + (((size_t)(rowTile * 8 + w)) << 13) + (l << 4);
    const char* gBh0 = (const char*)BhF + (((size_t)(colTile * 16 + w)) << 13) + (l << 4);
    const char* gBh1 = gBh0 + (8ll << 13);
    const char* gBl0 = (const char*)BlF + (((size_t)(colTile * 16 + w)) << 13) + (l << 4);
    const char* gBl1 = gBl0 + (8ll << 13);

    char* SB = (char*)S;
    int aOff = w << 10;
    int bOff0 = 8192 + (w << 10);
    int bOff1 = 8192 + ((8 + w) << 10);

#define ISSUE_H(s, b) do { int so = (s) << 10; char* bp = SB + (b) * 24576; \
    gll16(gAh + so, bp + aOff); gll16(gBh0 + so, bp + bOff0); gll16(gBh1 + so, bp + bOff1); } while (0)
#define ISSUE_L(s, b) do { int so = (s) << 10; char* bp = SB + (b) * 24576; \
    gll16(gAl + so, bp + aOff); gll16(gBl0 + so, bp + bOff0); gll16(gBl1 + so, bp + bOff1); } while (0)
#define READ_A(b, dst) do { const char* bp = SB + (b) * 24576; \
    _Pragma("unroll") for (int mf = 0; mf < 4; ++mf) \
        dst[mf] = *(const h8*)(bp + (((wm * 4 + mf) << 10) + (l << 4))); } while (0)
#define READ_B(b, dst) do { const char* bp = SB + (b) * 24576 + 8192; \
    _Pragma("unroll") for (int nf = 0; nf < 4; ++nf) \
        dst[nf] = *(const h8*)(bp + (((wn * 4 + nf) << 10) + (l << 4))); } while (0)
#define MFMA16(A_, B_) do { _Pragma("unroll") for (int mf = 0; mf < 4; ++mf) \
    _Pragma("unroll") for (int nf = 0; nf < 4; ++nf) \
        acc[mf][nf] = __builtin_amdgcn_mfma_f32_16x16x32_f16(A_[mf], B_[nf], acc[mf][nf], 0, 0, 0); } while (0)
#define PRIO1 __builtin_amdgcn_s_setprio(1)
#define PRIO0 __builtin_amdgcn_s_setprio(0)

    f4 acc[4][4];
#pragma unroll
    for (int i = 0; i < 4; ++i)
#pragma unroll
        for (int j = 0; j < 4; ++j) acc[i][j] = (f4)0.0f;

    h8 ah[4], bh[4], al[4], bl[4];

    // prologue: stages 0 (H0->buf0), 1 (L0->buf1), 2 (H1->buf2)
    ISSUE_H(0, 0); ISSUE_L(0, 1); ISSUE_H(1, 2);

    for (int s = 0; s < 6; s += 2) {
        // phase H(s): buf0
        WAITV(6); BARRIER; ISSUE_L(s + 1, 3); READ_A(0, ah); READ_B(0, bh);
        PRIO1; MFMA16(ah, bh); PRIO0;
        // phase L(s): buf1
        WAITV(6); BARRIER; ISSUE_H(s + 2, 0); READ_A(1, al); READ_B(1, bl);
        PRIO1; MFMA16(ah, bl); MFMA16(al, bh); PRIO0;
        // phase H(s+1): buf2
        WAITV(6); BARRIER; ISSUE_L(s + 2, 1); READ_A(2, ah); READ_B(2, bh);
        PRIO1; MFMA16(ah, bh); PRIO0;
        // phase L(s+1): buf3
        WAITV(6); BARRIER; ISSUE_H(s + 3, 2); READ_A(3, al); READ_B(3, bl);
        PRIO1; MFMA16(ah, bl); MFMA16(al, bh); PRIO0;
    }
    // tail: phases 12..15 (steps 6,7)
    WAITV(6); BARRIER; ISSUE_L(7, 3); READ_A(0, ah); READ_B(0, bh);
    PRIO1; MFMA16(ah, bh); PRIO0;
    WAITV(6); BARRIER; READ_A(1, al); READ_B(1, bl);
    PRIO1; MFMA16(ah, bl); MFMA16(al, bh); PRIO0;
    WAITV(3); BARRIER; READ_A(2, ah); READ_B(2, bh);
    PRIO1; MFMA16(ah, bh); PRIO0;
    WAITV(0); BARRIER; READ_A(3, al); READ_B(3, bl);
    PRIO1; MFMA16(ah, bl); MFMA16(al, bh); PRIO0;

    // ---- scores + per-row argmin over this block's 256 codes ----
    float* smV = (float*)S;        // overlays buf0 A-region (phase-15 readers use buf3)
    int* smI = (int*)S + 512;

    float esq[4];
#pragma unroll
    for (int nf = 0; nf < 4; ++nf) esq[nf] = e_sq[c0 + wn * 64 + nf * 16 + l16];

#pragma unroll
    for (int mf = 0; mf < 4; ++mf) {
#pragma unroll
        for (int rg = 0; rg < 4; ++rg) {
            float bestV = 3.4e38f;
            int bestI = 0;
#pragma unroll
            for (int nf = 0; nf < 4; ++nf) {
                float v = esq[nf] - 2.0f * acc[mf][nf][rg];
                int ci = c0 + wn * 64 + nf * 16 + l16;
                if (v < bestV || (v == bestV && ci < bestI)) { bestV = v; bestI = ci; }
            }
#pragma unroll
            for (int off = 1; off < 16; off <<= 1) {
                float vv = __shfl_xor(bestV, off);
                int ii = __shfl_xor(bestI, off);
                if (vv < bestV || (vv == bestV && ii < bestI)) { bestV = vv; bestI = ii; }
            }
            if (l16 == 0) {
                int rloc = wm * 64 + mf * 16 + lhi * 4 + rg;
                smV[wn * 128 + rloc] = bestV;
                smI[wn * 128 + rloc] = bestI;
            }
        }
    }
    __syncthreads();
    if (t < 128) {
        float bestV = smV[t];
        int bestI = smI[t];
#pragma unroll
        for (int wn2 = 1; wn2 < 4; ++wn2) {
            float v = smV[wn2 * 128 + t];
            int i2 = smI[wn2 * 128 + t];
            if (v < bestV || (v == bestV && i2 < bestI)) { bestV = v; bestI = i2; }
        }
        pV1[colTile * N_TOK + r0 + t] = bestV;
        pI1[colTile * N_TOK + r0 + t] = bestI;
    }
}

// ------ K3: combine partials -> final index, then gather quantized_flat ------
__global__ void k_final_out1(const float* __restrict__ pV1, const int* __restrict__ pI1,
                             const float* __restrict__ emb,
                             float* __restrict__ out2, int* __restrict__ idxI,
                             float* __restrict__ out1) {
    __shared__ int sidx[256];
    int t = threadIdx.x;
    int n0 = blockIdx.x * 256;
    int n = n0 + t;
    float v1 = pV1[n];
    int i1 = pI1[n];
#pragma unroll
    for (int ct = 1; ct < 4; ++ct) {
        float a1 = pV1[ct * N_TOK + n];
        int ai = pI1[ct * N_TOK + n];
        if (a1 < v1 || (a1 == v1 && ai < i1)) { v1 = a1; i1 = ai; }
    }
    out2[n] = (float)i1;
    idxI[n] = i1;
    sidx[t] = i1;
    __syncthreads();
    int rr = t >> 2, q = t & 3;
#pragma unroll
    for (int i = 0; i < 4; ++i) {
        int r = i * 64 + rr;
        int idx = sidx[r];
        const float* src = emb + (size_t)idx * DIM + q * 64;
        float* dst = out1 + (size_t)(n0 + r) * DIM + q * 64;
#pragma unroll
        for (int j = 0; j < 16; ++j)
            *(float4*)(dst + j * 4) = *(const float4*)(src + j * 4);
    }
}

// ---------------- K4: quantized[B,C,H,W] via LDS transpose -------------------
__global__ void k_out3(const float* __restrict__ emb, const int* __restrict__ idxI,
                       float* __restrict__ out3) {
    __shared__ float E[32][257];
    int blk = blockIdx.x;
    int b = blk >> 7, hwt = blk & 127;
    int hw0 = hwt * 32;
    int n0 = b * HWSZ + hw0;
    int t = threadIdx.x;
    {
        int r = t >> 3, oct = t & 7;
        int idx = idxI[n0 + r];
        const float* src = emb + (size_t)idx * DIM + oct * 32;
#pragma unroll
        for (int i = 0; i < 8; ++i) {
            float4 v = *(const float4*)(src + i * 4);
            E[r][oct * 32 + i * 4 + 0] = v.x;
            E[r][oct * 32 + i * 4 + 1] = v.y;
            E[r][oct * 32 + i * 4 + 2] = v.z;
            E[r][oct * 32 + i * 4 + 3] = v.w;
        }
    }
    __syncthreads();
    {
        int w = t >> 6, l = t & 63;
        int ch = l >> 5, hw = l & 31;
        float* dst = out3 + (size_t)b * DIM * HWSZ + hw0 + hw;
#pragma unroll
        for (int it = 0; it < 32; ++it) {
            int c = w * 64 + it * 2 + ch;
            dst[(size_t)c * HWSZ] = E[hw][c];
        }
    }
}

extern "C" void kernel_launch(void* const* d_in, const int* in_sizes, int n_in,
                              void* d_out, int out_size, void* d_ws, size_t ws_size,
                              hipStream_t stream) {
    const float* z = (const float*)d_in[0];
    const float* emb = (const float*)d_in[1];
    float* out = (float*)d_out;
    float* out0 = out;                    // encoded_flat  [65536,256]
    float* out1 = out + 16777216;         // quantized_flat[65536,256]
    float* out2 = out + 33554432;         // indices       [65536] (as float)
    float* out3 = out + 33619968;         // quantized     [16,256,64,64]

    // A-operand fp16 hi/lo scratch fills the out1 region (64 MB); out1 is
    // written afterwards by k_final_out1.
    _Float16* AhF = (_Float16*)out1;
    _Float16* AlF = (_Float16*)(out1 + 8388608);

    char* ws = (char*)d_ws;
    _Float16* BhF = (_Float16*)(ws);                 // 512 KB
    _Float16* BlF = (_Float16*)(ws + 524288);        // 512 KB
    float* e_sq = (float*)(ws + 1048576);            // 4 KB
    float* pV1 = (float*)(ws + 1052672);             // 1 MB
    int* pI1 = (int*)(ws + 2101248);                 // 1 MB
    int* idxI = (int*)(ws + 3149824);                // 256 KB

    k_prep_frag<<<128, 256, 0, stream>>>(emb, BhF, BlF);
    k_esq<<<256, 256, 0, stream>>>(emb, e_sq);
    k_transpose<<<4096, 256, 0, stream>>>(z, out0, AhF, AlF);
    k_gemm_argmin<<<2048, 512, 0, stream>>>(AhF, AlF, BhF, BlF, e_sq, pV1, pI1);
    k_final_out1<<<256, 256, 0, stream>>>(pV1, pI1, emb, out2, idxI, out1);
    k_out3<<<2048, 256, 0, stream>>>(emb, idxI, out3);
}

// Round 6
// 209.881 us; speedup vs baseline: 1.4844x; 1.2126x over previous
//
#include <hip/hip_runtime.h>
#include <hip/hip_bf16.h>

typedef _Float16 h8 __attribute__((ext_vector_type(8)));
typedef float f4 __attribute__((ext_vector_type(4)));

#define N_TOK 65536
#define DIM 256
#define KCODES 1024
#define HWSZ 4096

// async global->LDS, 16B per lane. LDS dest = wave-uniform base + lane*16.
__device__ __forceinline__ void gll16(const void* g, void* l) {
    __builtin_amdgcn_global_load_lds((const __attribute__((address_space(1))) void*)g,
                                     (__attribute__((address_space(3))) void*)l, 16, 0, 0);
}

// Fragment layout (A and B operands, 16x16x32 f16 MFMA):
//   element (n, d) -> granule G = ((n>>4)*8 + (d>>5))*64 + ((d>>3)&3)*16 + (n&15),
//   half j = d&7 inside the 16B granule. Conflict-free ds_read_b128, linear gll16.

// ---------------- K0a: embedding -> fragment-layout fp16 hi/lo ---------------
__global__ void k_prep_frag(const float* __restrict__ emb, _Float16* __restrict__ BhF,
                            _Float16* __restrict__ BlF) {
    int gi = blockIdx.x * 256 + threadIdx.x;      // granule index, 0..32767
    int kb = gi >> 9;
    int s = (gi >> 6) & 7;
    int dq = (gi >> 4) & 3;
    int r = gi & 15;
    int code = kb * 16 + r;
    int d0 = s * 32 + dq * 8;
    const float* src = emb + (size_t)code * DIM + d0;
    float4 x0 = *(const float4*)(src);
    float4 x1 = *(const float4*)(src + 4);
    float xs[8] = {x0.x, x0.y, x0.z, x0.w, x1.x, x1.y, x1.z, x1.w};
    h8 hi, lo;
#pragma unroll
    for (int j = 0; j < 8; ++j) {
        _Float16 h = (_Float16)xs[j];
        hi[j] = h;
        lo[j] = (_Float16)(xs[j] - (float)h);
    }
    *(h8*)(BhF + (size_t)gi * 8) = hi;
    *(h8*)(BlF + (size_t)gi * 8) = lo;
}

// ---------------- K0b: e_sq ---------------------------------------------------
__global__ void k_esq(const float* __restrict__ emb, float* __restrict__ e_sq) {
    int t = threadIdx.x;
    int code = blockIdx.x * 4 + (t >> 6);
    int l = t & 63;
    float4 v = *(const float4*)(emb + (size_t)code * DIM + l * 4);
    float s = v.x * v.x + v.y * v.y + v.z * v.z + v.w * v.w;
#pragma unroll
    for (int off = 32; off >= 1; off >>= 1) s += __shfl_xor(s, off);
    if (l == 0) e_sq[code] = s;
}

// ------- K1: transpose z[B,C,H,W] -> enc[N,C] + fragment fp16 hi/lo ----------
__global__ void k_transpose(const float* __restrict__ z, float* __restrict__ enc,
                            _Float16* __restrict__ AhF, _Float16* __restrict__ AlF) {
    __shared__ float T[64][65];
    int blk = blockIdx.x;
    int b = blk >> 8;
    int rem = blk & 255;
    int c0 = (rem >> 6) * 64;
    int hw0 = (rem & 63) * 64;
    int t = threadIdx.x;
    const float* zp = z + (size_t)b * DIM * HWSZ;
    {
        int hw4 = (t & 15) * 4, cl = t >> 4;
#pragma unroll
        for (int i = 0; i < 4; ++i) {
            int c = cl + i * 16;
            float4 v = *(const float4*)(zp + (size_t)(c0 + c) * HWSZ + hw0 + hw4);
            T[c][hw4 + 0] = v.x; T[c][hw4 + 1] = v.y;
            T[c][hw4 + 2] = v.z; T[c][hw4 + 3] = v.w;
        }
    }
    __syncthreads();
    // enc fp32 (output 0)
    {
        int c4 = (t & 15) * 4, hwl = t >> 4;
#pragma unroll
        for (int i = 0; i < 4; ++i) {
            int hw = hwl + i * 16;
            float4 v;
            v.x = T[c4 + 0][hw]; v.y = T[c4 + 1][hw];
            v.z = T[c4 + 2][hw]; v.w = T[c4 + 3][hw];
            *(float4*)(enc + (size_t)(b * HWSZ + hw0 + hw) * DIM + c0 + c4) = v;
        }
    }
    // fragment-layout fp16 hi/lo
    {
        int base_nb = b * 256 + (hw0 >> 4);
#pragma unroll
        for (int i = 0; i < 2; ++i) {
            int gidx = i * 256 + t;
            int nbi = gidx >> 7;
            int si = (gidx >> 6) & 1;
            int dq = (gidx >> 4) & 3;
            int r = gidx & 15;
            int hwl = nbi * 16 + r;
            int cl = si * 32 + dq * 8;
            h8 hi, lo;
#pragma unroll
            for (int j = 0; j < 8; ++j) {
                float x = T[cl + j][hwl];
                _Float16 h = (_Float16)x;
                hi[j] = h;
                lo[j] = (_Float16)(x - (float)h);
            }
            size_t G = (((size_t)(base_nb + nbi) * 8) + (c0 >> 5) + si) * 64 + dq * 16 + r;
            *(h8*)(AhF + G * 8) = hi;
            *(h8*)(AlF + G * 8) = lo;
        }
    }
}

// ---- K2: GEMM (fp16 split, 3 passes), 6-buf deep pipeline, counted vmcnt ----
#define WAITV(n) asm volatile("s_waitcnt vmcnt(" #n ")" ::: "memory")
#define BARRIER __builtin_amdgcn_s_barrier()
#define PRIO1 __builtin_amdgcn_s_setprio(1)
#define PRIO0 __builtin_amdgcn_s_setprio(0)

extern __shared__ char SB[];   // 6 bufs x 24 KB = 144 KB; buf = [A 8KB][B 16KB]

__global__ __launch_bounds__(1024)
void k_gemm_argmin(const _Float16* __restrict__ AhF, const _Float16* __restrict__ AlF,
                   const _Float16* __restrict__ BhF, const _Float16* __restrict__ BlF,
                   const float* __restrict__ e_sq,
                   float* __restrict__ pV1, int* __restrict__ pI1) {
    int gid = blockIdx.x;
    // super-row ordering: A chunk (8 MB) stays L3-hot across the 4 colTiles
    int rchunk = gid >> 8;
    int colTile = (gid >> 6) & 3;
    int rowTile = rchunk * 64 + (gid & 63);
    int r0 = rowTile * 128, c0 = colTile * 256;
    int t = threadIdx.x;
    int w = t >> 6, l = t & 63;           // 16 waves
    int wm = w >> 2, wn = w & 3;          // wave tile 32x64
    int l16 = l & 15, lhi = l >> 4;

    // stager waves 0..7: 1 A-load + 2 B-loads per phase
    const char* gAh = (const char*)AhF + (((size_t)(rowTile * 8 + w)) << 13) + (l << 4);
    const char* gAl = (const char*)AlF + (((size_t)(rowTile * 8 + w)) << 13) + (l << 4);
    const char* gBh0 = (const char*)BhF + (((size_t)(colTile * 16 + 2 * w)) << 13) + (l << 4);
    const char* gBh1 = gBh0 + (1ll << 13);
    const char* gBl0 = (const char*)BlF + (((size_t)(colTile * 16 + 2 * w)) << 13) + (l << 4);
    const char* gBl1 = gBl0 + (1ll << 13);

#define ISSUE_P(p) do { \
    const int s_ = (p) >> 1, buf_ = (p) % 6; \
    const char* a_ = ((p) & 1) ? gAl : gAh; \
    const char* b0_ = ((p) & 1) ? gBl0 : gBh0; \
    const char* b1_ = ((p) & 1) ? gBl1 : gBh1; \
    char* bp_ = SB + buf_ * 24576; \
    gll16(a_ + (s_ << 10), bp_ + (w << 10)); \
    gll16(b0_ + (s_ << 10), bp_ + 8192 + ((2 * w) << 10)); \
    gll16(b1_ + (s_ << 10), bp_ + 8192 + ((2 * w + 1) << 10)); \
} while (0)

#define READ_A(buf, dst) { const char* bp_ = SB + (buf) * 24576; \
    _Pragma("unroll") for (int mf = 0; mf < 2; ++mf) \
        dst[mf] = *(const h8*)(bp_ + ((wm * 2 + mf) << 10) + (l << 4)); }
#define READ_B(buf, dst) { const char* bp_ = SB + (buf) * 24576 + 8192; \
    _Pragma("unroll") for (int nf = 0; nf < 4; ++nf) \
        dst[nf] = *(const h8*)(bp_ + ((wn * 4 + nf) << 10) + (l << 4)); }
#define MFMA8(A_, B_) { _Pragma("unroll") for (int mf = 0; mf < 2; ++mf) \
    _Pragma("unroll") for (int nf = 0; nf < 4; ++nf) \
        acc[mf][nf] = __builtin_amdgcn_mfma_f32_16x16x32_f16(A_[mf], B_[nf], acc[mf][nf], 0, 0, 0); }

// phase q: even = H(step q/2): hh; odd = L(step q/2): hl + lh
#define PHASE(q, W, DO_ISSUE) \
    if (w < 8) { WAITV(W); } \
    BARRIER; \
    if ((DO_ISSUE) && w < 8) { ISSUE_P((q) + 5); } \
    if (((q) & 1) == 0) { \
        READ_A((q) % 6, ah); READ_B((q) % 6, bh); \
        PRIO1; MFMA8(ah, bh); PRIO0; \
    } else { \
        READ_A((q) % 6, al); READ_B((q) % 6, bl); \
        PRIO1; MFMA8(ah, bl); MFMA8(al, bh); PRIO0; \
    }

    f4 acc[2][4];
#pragma unroll
    for (int i = 0; i < 2; ++i)
#pragma unroll
        for (int j = 0; j < 4; ++j) acc[i][j] = (f4)0.0f;

    h8 ah[2], al[2], bh[4], bl[4];

    // prologue: 5 phases in flight (15 loads per stager wave)
    if (w < 8) { ISSUE_P(0); ISSUE_P(1); ISSUE_P(2); ISSUE_P(3); ISSUE_P(4); }

    PHASE(0, 12, 1)  PHASE(1, 12, 1)  PHASE(2, 12, 1)  PHASE(3, 12, 1)
    PHASE(4, 12, 1)  PHASE(5, 12, 1)  PHASE(6, 12, 1)  PHASE(7, 12, 1)
    PHASE(8, 12, 1)  PHASE(9, 12, 1)  PHASE(10, 12, 1) PHASE(11, 12, 0)
    PHASE(12, 9, 0)  PHASE(13, 6, 0)  PHASE(14, 3, 0)  PHASE(15, 0, 0)

    // ---- scores + per-row argmin over this block's 256 codes ----
    // overlay buf0 (last compute used buf3; all waves past phase-15 barrier)
    float* smV = (float*)SB;          // [4][128]
    int* smI = (int*)(SB + 2048);

    float esq[4];
#pragma unroll
    for (int nf = 0; nf < 4; ++nf) esq[nf] = e_sq[c0 + wn * 64 + nf * 16 + l16];

#pragma unroll
    for (int mf = 0; mf < 2; ++mf) {
#pragma unroll
        for (int rg = 0; rg < 4; ++rg) {
            float bestV = 3.4e38f;
            int bestI = 0;
#pragma unroll
            for (int nf = 0; nf < 4; ++nf) {
                float v = esq[nf] - 2.0f * acc[mf][nf][rg];
                int ci = c0 + wn * 64 + nf * 16 + l16;
                if (v < bestV || (v == bestV && ci < bestI)) { bestV = v; bestI = ci; }
            }
#pragma unroll
            for (int off = 1; off < 16; off <<= 1) {
                float vv = __shfl_xor(bestV, off);
                int ii = __shfl_xor(bestI, off);
                if (vv < bestV || (vv == bestV && ii < bestI)) { bestV = vv; bestI = ii; }
            }
            if (l16 == 0) {
                int rloc = wm * 32 + mf * 16 + lhi * 4 + rg;
                smV[wn * 128 + rloc] = bestV;
                smI[wn * 128 + rloc] = bestI;
            }
        }
    }
    __syncthreads();
    if (t < 128) {
        float bestV = smV[t];
        int bestI = smI[t];
#pragma unroll
        for (int wn2 = 1; wn2 < 4; ++wn2) {
            float v = smV[wn2 * 128 + t];
            int i2 = smI[wn2 * 128 + t];
            if (v < bestV || (v == bestV && i2 < bestI)) { bestV = v; bestI = i2; }
        }
        pV1[colTile * N_TOK + r0 + t] = bestV;
        pI1[colTile * N_TOK + r0 + t] = bestI;
    }
}

// ------ K3: combine partials -> final index, then gather quantized_flat ------
__global__ void k_final_out1(const float* __restrict__ pV1, const int* __restrict__ pI1,
                             const float* __restrict__ emb,
                             float* __restrict__ out2, int* __restrict__ idxI,
                             float* __restrict__ out1) {
    __shared__ int sidx[256];
    int t = threadIdx.x;
    int n0 = blockIdx.x * 256;
    int n = n0 + t;
    float v1 = pV1[n];
    int i1 = pI1[n];
#pragma unroll
    for (int ct = 1; ct < 4; ++ct) {
        float a1 = pV1[ct * N_TOK + n];
        int ai = pI1[ct * N_TOK + n];
        if (a1 < v1 || (a1 == v1 && ai < i1)) { v1 = a1; i1 = ai; }
    }
    out2[n] = (float)i1;
    idxI[n] = i1;
    sidx[t] = i1;
    __syncthreads();
    int rr = t >> 2, q = t & 3;
#pragma unroll
    for (int i = 0; i < 4; ++i) {
        int r = i * 64 + rr;
        int idx = sidx[r];
        const float* src = emb + (size_t)idx * DIM + q * 64;
        float* dst = out1 + (size_t)(n0 + r) * DIM + q * 64;
#pragma unroll
        for (int j = 0; j < 16; ++j)
            *(float4*)(dst + j * 4) = *(const float4*)(src + j * 4);
    }
}

// ---------------- K4: quantized[B,C,H,W] via LDS transpose -------------------
__global__ void k_out3(const float* __restrict__ emb, const int* __restrict__ idxI,
                       float* __restrict__ out3) {
    __shared__ float E[32][257];
    int blk = blockIdx.x;
    int b = blk >> 7, hwt = blk & 127;
    int hw0 = hwt * 32;
    int n0 = b * HWSZ + hw0;
    int t = threadIdx.x;
    {
        int r = t >> 3, oct = t & 7;
        int idx = idxI[n0 + r];
        const float* src = emb + (size_t)idx * DIM + oct * 32;
#pragma unroll
        for (int i = 0; i < 8; ++i) {
            float4 v = *(const float4*)(src + i * 4);
            E[r][oct * 32 + i * 4 + 0] = v.x;
            E[r][oct * 32 + i * 4 + 1] = v.y;
            E[r][oct * 32 + i * 4 + 2] = v.z;
            E[r][oct * 32 + i * 4 + 3] = v.w;
        }
    }
    __syncthreads();
    {
        int w = t >> 6, l = t & 63;
        int ch = l >> 5, hw = l & 31;
        float* dst = out3 + (size_t)b * DIM * HWSZ + hw0 + hw;
#pragma unroll
        for (int it = 0; it < 32; ++it) {
            int c = w * 64 + it * 2 + ch;
            dst[(size_t)c * HWSZ] = E[hw][c];
        }
    }
}

extern "C" void kernel_launch(void* const* d_in, const int* in_sizes, int n_in,
                              void* d_out, int out_size, void* d_ws, size_t ws_size,
                              hipStream_t stream) {
    const float* z = (const float*)d_in[0];
    const float* emb = (const float*)d_in[1];
    float* out = (float*)d_out;
    float* out0 = out;                    // encoded_flat  [65536,256]
    float* out1 = out + 16777216;         // quantized_flat[65536,256]
    float* out2 = out + 33554432;         // indices       [65536] (as float)
    float* out3 = out + 33619968;         // quantized     [16,256,64,64]

    // A-operand fp16 hi/lo scratch fills the out1 region (64 MB); out1 is
    // written afterwards by k_final_out1.
    _Float16* AhF = (_Float16*)out1;
    _Float16* AlF = (_Float16*)(out1 + 8388608);

    char* ws = (char*)d_ws;
    _Float16* BhF = (_Float16*)(ws);                 // 512 KB
    _Float16* BlF = (_Float16*)(ws + 524288);        // 512 KB
    float* e_sq = (float*)(ws + 1048576);            // 4 KB
    float* pV1 = (float*)(ws + 1052672);             // 1 MB
    int* pI1 = (int*)(ws + 2101248);                 // 1 MB
    int* idxI = (int*)(ws + 3149824);                // 256 KB

    static bool attr_set = false;
    if (!attr_set) {
        hipFuncSetAttribute((const void*)k_gemm_argmin,
                            hipFuncAttributeMaxDynamicSharedMemorySize, 147456);
        attr_set = true;
    }

    k_prep_frag<<<128, 256, 0, stream>>>(emb, BhF, BlF);
    k_esq<<<256, 256, 0, stream>>>(emb, e_sq);
    k_transpose<<<4096, 256, 0, stream>>>(z, out0, AhF, AlF);
    k_gemm_argmin<<<2048, 1024, 147456, stream>>>(AhF, AlF, BhF, BlF, e_sq, pV1, pI1);
    k_final_out1<<<256, 256, 0, stream>>>(pV1, pI1, emb, out2, idxI, out1);
    k_out3<<<2048, 256, 0, stream>>>(emb, idxI, out3);
}